// Round 2
// baseline (599.710 us; speedup 1.0000x reference)
//
#include <hip/hip_runtime.h>
#include <stdint.h>

#define N_NODES 20000
#define N_EDGES 320000
#define EMB     256
#define D_IN    300
#define KPAD0   320   // D_IN padded to multiple of 32
#define SROW    260   // LDS row stride in floats (multiple of 4 -> 16B-aligned float4)
#define MROWS   32    // block M-tile (reverted: 16-row tile doubled weight traffic, +20%)

// src-chunked aggregation: chunk of 2048 nodes = 2MB of F rows, fits 4MB/XCD L2
#define CHUNK_BITS 11
#define CHUNK   2048
#define NC      10    // ceil(20000/2048)
#define NSL     79    // warming slices per chunk = blocks per XCD (625/8)
#define PFU     7     // float4 prefetch loads per thread per chunk (7*256*16B >= 2MB/79)

typedef __attribute__((ext_vector_type(8))) short s16x8;   // 8 bf16 operand (4 VGPRs)
typedef __attribute__((ext_vector_type(4))) float f32x4;

static __device__ __forceinline__ float bf2f(unsigned short u) {
    union { unsigned u; float f; } x; x.u = ((unsigned)u) << 16; return x.f;
}
static __device__ __forceinline__ unsigned short f2bf(float f) {
    union { float f; unsigned u; } x; x.f = f;
    unsigned r = x.u + 0x7fffu + ((x.u >> 16) & 1u);   // RNE
    return (unsigned short)(r >> 16);
}
// split v = hi + lo (each bf16), |err| <= 2^-18 |v|
static __device__ __forceinline__ void split_bf(float v, unsigned short& h, unsigned short& l) {
    h = f2bf(v);
    l = f2bf(v - bf2f(h));
}
static __device__ __forceinline__ void split8(const float* fv, s16x8& hi, s16x8& lo) {
#pragma unroll
    for (int j = 0; j < 8; ++j) {
        unsigned short h, l;
        split_bf(fv[j], h, l);
        hi[j] = (short)h; lo[j] = (short)l;
    }
}

// ---------------- chunked CSR build (4 dispatches) ----------------

__global__ void k_init2(int* deg2, int* cursor2, int n) {
    int i = blockIdx.x * 256 + threadIdx.x;
    if (i < n) { deg2[i] = 0; cursor2[i] = 0; }
}

__global__ void k_deg2(const int* __restrict__ src, const int* __restrict__ dst,
                       int* __restrict__ deg2, int e) {
    int i = blockIdx.x * 256 + threadIdx.x;
    if (i < e) {
        int s = src[i], d = dst[i];
        atomicAdd(&deg2[d * NC + (s >> CHUNK_BITS)], 1);
    }
}

// single-block: exclusive scan over flat deg2[n*NC] -> ro2[0..n*NC], plus dinv
__global__ void k_scan2(const int* __restrict__ deg2, int* __restrict__ ro2,
                        float* __restrict__ dinv) {
    __shared__ int sums[1024];
    int tid = threadIdx.x;
    const int NPT = 20;                       // nodes per thread (1024*20 >= 20000)
    int n0 = tid * NPT; if (n0 > N_NODES) n0 = N_NODES;
    int n1 = n0 + NPT;  if (n1 > N_NODES) n1 = N_NODES;
    int s = 0;
    for (int n = n0; n < n1; ++n) {
        int rs = 0;
#pragma unroll
        for (int c = 0; c < NC; ++c) rs += deg2[n * NC + c];
        dinv[n] = rsqrtf((float)(rs + 1));    // +1 self-loop
        s += rs;
    }
    sums[tid] = s;
    __syncthreads();
    for (int off = 1; off < 1024; off <<= 1) {
        int v = (tid >= off) ? sums[tid - off] : 0;
        __syncthreads();
        sums[tid] += v;
        __syncthreads();
    }
    int excl = (tid == 0) ? 0 : sums[tid - 1];
    for (int n = n0; n < n1; ++n)
#pragma unroll
        for (int c = 0; c < NC; ++c) {
            ro2[n * NC + c] = excl;
            excl += deg2[n * NC + c];
        }
    if (tid == 1023) ro2[N_NODES * NC] = sums[1023];
}

__global__ void k_scatter2(const int* __restrict__ src, const int* __restrict__ dst,
                           const int* __restrict__ ro2, int* __restrict__ cursor2,
                           const float* __restrict__ dinv,
                           int* __restrict__ csr_src, float* __restrict__ csr_norm, int e) {
    int i = blockIdx.x * 256 + threadIdx.x;
    if (i >= e) return;
    int s = src[i], d = dst[i];
    int slot = d * NC + (s >> CHUNK_BITS);
    int pos = ro2[slot] + atomicAdd(&cursor2[slot], 1);
    csr_src[pos]  = s;
    csr_norm[pos] = dinv[s] * dinv[d];
}

// ---------------- batched weight transpose+split (1 dispatch for all 6) ----------------

struct WSplitArgs {
    const float* w[6];
    unsigned short* th[6];
    unsigned short* tl[6];
};

__global__ void k_wsplit_all(WSplitArgs a) {
#pragma unroll
    for (int l = 0; l < 6; ++l) {
        const int K    = (l == 0) ? D_IN  : EMB;
        const int Kpad = (l == 0) ? KPAD0 : EMB;
        const int tot  = EMB * Kpad;
        for (int idx = blockIdx.x * 256 + threadIdx.x; idx < tot; idx += gridDim.x * 256) {
            int n = idx / Kpad, k = idx - n * Kpad;
            float v = (k < K) ? a.w[l][k * EMB + n] : 0.f;
            unsigned short h, lo;
            split_bf(v, h, lo);
            a.th[l][idx] = h; a.tl[l][idx] = lo;
        }
    }
}

// ---------------- conv0 GEMM: C[M,256] = x[M,300] @ W0, f32 in/out ----------------
// block = 4 waves; block tile 32 rows x 256 cols; wave tile 32x64 (MT=2).

__global__ __launch_bounds__(256) void k_gemm0(
    const float* __restrict__ A,
    const unsigned short* __restrict__ Wth,
    const unsigned short* __restrict__ Wtl,
    float* __restrict__ C)
{
    int tid  = threadIdx.x;
    int lane = tid & 63, wave = tid >> 6;
    int quad = lane >> 4, l16 = lane & 15;
    int m_base = blockIdx.x * 32;

    f32x4 acc[2][4];
#pragma unroll
    for (int mt = 0; mt < 2; ++mt)
#pragma unroll
        for (int nt = 0; nt < 4; ++nt) acc[mt][nt] = (f32x4){0.f, 0.f, 0.f, 0.f};

    for (int ks = 0; ks < KPAD0 / 32; ++ks) {
        int k0 = ks * 32 + quad * 8;
        s16x8 ah[2], al[2], bh[4], bl[4];
#pragma unroll
        for (int nt = 0; nt < 4; ++nt) {
            int nn = wave * 64 + nt * 16 + l16;
            bh[nt] = *(const s16x8*)(Wth + (size_t)nn * KPAD0 + k0);
            bl[nt] = *(const s16x8*)(Wtl + (size_t)nn * KPAD0 + k0);
        }
#pragma unroll
        for (int mt = 0; mt < 2; ++mt) {
            int row = m_base + mt * 16 + l16;
            const float* ar = A + (size_t)row * D_IN;
            float fv[8];
            if (row == N_NODES - 1 && k0 + 8 > D_IN) {
#pragma unroll
                for (int j = 0; j < 8; ++j) {
                    int kk = k0 + j;
                    fv[j] = (kk < D_IN) ? ar[kk] : 0.f;
                }
            } else {
                // k past 299 reads next row's data; harmless: Wt zero-padded there.
                *(float4*)(fv)     = *(const float4*)(ar + k0);
                *(float4*)(fv + 4) = *(const float4*)(ar + k0 + 4);
            }
            split8(fv, ah[mt], al[mt]);
        }
#pragma unroll
        for (int mt = 0; mt < 2; ++mt)
#pragma unroll
            for (int nt = 0; nt < 4; ++nt) {
                acc[mt][nt] = __builtin_amdgcn_mfma_f32_16x16x32_bf16(ah[mt], bh[nt], acc[mt][nt], 0, 0, 0);
                acc[mt][nt] = __builtin_amdgcn_mfma_f32_16x16x32_bf16(ah[mt], bl[nt], acc[mt][nt], 0, 0, 0);
                acc[mt][nt] = __builtin_amdgcn_mfma_f32_16x16x32_bf16(al[mt], bh[nt], acc[mt][nt], 0, 0, 0);
            }
    }

#pragma unroll
    for (int mt = 0; mt < 2; ++mt)
#pragma unroll
        for (int r = 0; r < 4; ++r) {
            int row = m_base + mt * 16 + quad * 4 + r;
#pragma unroll
            for (int nt = 0; nt < 4; ++nt) {
                int col = wave * 64 + nt * 16 + l16;
                C[(size_t)row * EMB + col] = acc[mt][nt][r];
            }
        }
}

// ---------------- shared device pieces for fused kernels ----------------

// chunked aggregate: 32 nodes/block, wave owns 8 nodes, lane owns 4 dims.
// Iterate src-chunks; gathers of chunk c hit L2 because chunk c was streamed
// into this XCD's L2 during chunk c-1 (slice per block via bid>>3 under the
// round-robin block->XCD mapping). Prefetch regs sunk via asm AFTER the
// gathers so their waitcnt is free; warming is a pure perf hint (correct
// regardless of the actual block->XCD mapping).
static __device__ __forceinline__ void agg_to_lds_chunked(
    float (*S)[SROW], int nb, int wave, int lane, int tid, int bid,
    const float* __restrict__ Fin,
    const int* __restrict__ ro2, const int* __restrict__ csr_src,
    const float* __restrict__ csr_norm, const float* __restrict__ dinv,
    const float* __restrict__ bagg, int relu)
{
    const float4* F4 = (const float4*)Fin;
    float4 bb = *(const float4*)(bagg + lane * 4);
    int xslot = bid >> 3;

    float4 pf[PFU];
    // issue warming loads for chunk 0
    {
        int nf4 = CHUNK * 64;
        int sl  = (nf4 + NSL - 1) / NSL;
        int s0  = xslot * sl;
#pragma unroll
        for (int u = 0; u < PFU; ++u) {
            int i = s0 + tid + u * 256;
            i = (i < nf4) ? i : (nf4 - 1);
            pf[u] = F4[i];
        }
    }

    // init accumulators: bias + self-loop term (block rows are contiguous)
    float4 acc[8];
#pragma unroll
    for (int t = 0; t < 8; ++t) {
        int node = nb + wave * 8 + t;
        float dv = dinv[node];
        float ws = dv * dv;
        float4 sv = F4[(size_t)node * 64 + lane];
        acc[t].x = bb.x + ws * sv.x;
        acc[t].y = bb.y + ws * sv.y;
        acc[t].z = bb.z + ws * sv.z;
        acc[t].w = bb.w + ws * sv.w;
    }

    for (int c = 0; c < NC; ++c) {
        int js[8], jee[8];
        int nbase = (nb + wave * 8) * NC + c;
#pragma unroll
        for (int t = 0; t < 8; ++t) {
            js[t]  = ro2[nbase + t * NC];
            jee[t] = ro2[nbase + t * NC + 1];
        }
#pragma unroll
        for (int t = 0; t < 8; ++t) {
            int j = js[t], je_ = jee[t];
            for (; j + 1 < je_; j += 2) {
                int   s0 = csr_src[j],  s1 = csr_src[j + 1];
                float w0 = csr_norm[j], w1 = csr_norm[j + 1];
                float4 v0 = F4[(size_t)s0 * 64 + lane];
                float4 v1 = F4[(size_t)s1 * 64 + lane];
                acc[t].x += w0 * v0.x + w1 * v1.x;
                acc[t].y += w0 * v0.y + w1 * v1.y;
                acc[t].z += w0 * v0.z + w1 * v1.z;
                acc[t].w += w0 * v0.w + w1 * v1.w;
            }
            if (j < je_) {
                int   s = csr_src[j];
                float w = csr_norm[j];
                float4 v = F4[(size_t)s * 64 + lane];
                acc[t].x += w * v.x; acc[t].y += w * v.y;
                acc[t].z += w * v.z; acc[t].w += w * v.w;
            }
        }
        // keep warming loads alive; waitcnt here is free (returned during gathers)
#pragma unroll
        for (int u = 0; u < PFU; ++u)
            asm volatile("" :: "v"(pf[u].x), "v"(pf[u].y), "v"(pf[u].z), "v"(pf[u].w));
        // issue warming loads for chunk c+1
        if (c + 1 < NC) {
            int rows = N_NODES - (c + 1) * CHUNK; if (rows > CHUNK) rows = CHUNK;
            int nf4  = rows * 64;
            int base = (c + 1) * CHUNK * 64;
            int sl   = (nf4 + NSL - 1) / NSL;
            int s0   = xslot * sl;
#pragma unroll
            for (int u = 0; u < PFU; ++u) {
                int i = s0 + tid + u * 256;
                i = (i < nf4) ? i : (nf4 - 1);
                pf[u] = F4[base + i];
            }
        }
    }

#pragma unroll
    for (int t = 0; t < 8; ++t) {
        float4 o = acc[t];
        if (relu) {
            o.x = fmaxf(o.x, 0.f); o.y = fmaxf(o.y, 0.f);
            o.z = fmaxf(o.z, 0.f); o.w = fmaxf(o.w, 0.f);
        }
        *(float4*)&S[wave * 8 + t][lane * 4] = o;
    }
}

// one split-bf16 GEMM layer: acc = S[32x256] @ W (K=EMB), A from LDS, B from global pair
static __device__ __forceinline__ void gemm_layer(
    const float (*S)[SROW], int wave, int quad, int l16,
    const unsigned short* __restrict__ Wth,
    const unsigned short* __restrict__ Wtl,
    f32x4 acc[2][4])
{
#pragma unroll
    for (int mt = 0; mt < 2; ++mt)
#pragma unroll
        for (int nt = 0; nt < 4; ++nt) acc[mt][nt] = (f32x4){0.f, 0.f, 0.f, 0.f};

    for (int ks = 0; ks < EMB / 32; ++ks) {
        int k0 = ks * 32 + quad * 8;
        s16x8 ah[2], al[2], bh[4], bl[4];
#pragma unroll
        for (int nt = 0; nt < 4; ++nt) {
            int nn = wave * 64 + nt * 16 + l16;
            bh[nt] = *(const s16x8*)(Wth + (size_t)nn * EMB + k0);
            bl[nt] = *(const s16x8*)(Wtl + (size_t)nn * EMB + k0);
        }
#pragma unroll
        for (int mt = 0; mt < 2; ++mt) {
            float fv[8];
            *(float4*)(fv)     = *(const float4*)&S[mt * 16 + l16][k0];
            *(float4*)(fv + 4) = *(const float4*)&S[mt * 16 + l16][k0 + 4];
            split8(fv, ah[mt], al[mt]);
        }
#pragma unroll
        for (int mt = 0; mt < 2; ++mt)
#pragma unroll
            for (int nt = 0; nt < 4; ++nt) {
                acc[mt][nt] = __builtin_amdgcn_mfma_f32_16x16x32_bf16(ah[mt], bh[nt], acc[mt][nt], 0, 0, 0);
                acc[mt][nt] = __builtin_amdgcn_mfma_f32_16x16x32_bf16(ah[mt], bl[nt], acc[mt][nt], 0, 0, 0);
                acc[mt][nt] = __builtin_amdgcn_mfma_f32_16x16x32_bf16(al[mt], bh[nt], acc[mt][nt], 0, 0, 0);
            }
    }
}

// ---------------- fused conv: agg(Fin)+bias,relu -> LDS -> @W -> Fout (f32) ----------------

__global__ __launch_bounds__(256) void k_conv_fused(
    const float* __restrict__ Fin,
    const int* __restrict__ ro2, const int* __restrict__ csr_src,
    const float* __restrict__ csr_norm, const float* __restrict__ dinv,
    const float* __restrict__ bagg,
    const unsigned short* __restrict__ Wth, const unsigned short* __restrict__ Wtl,
    float* __restrict__ Fout)
{
    __shared__ float S[MROWS][SROW];
    int tid  = threadIdx.x;
    int lane = tid & 63, wave = tid >> 6;
    int quad = lane >> 4, l16 = lane & 15;
    int nb   = blockIdx.x * MROWS;

    agg_to_lds_chunked(S, nb, wave, lane, tid, blockIdx.x,
                       Fin, ro2, csr_src, csr_norm, dinv, bagg, 1);
    __syncthreads();

    f32x4 acc[2][4];
    gemm_layer(S, wave, quad, l16, Wth, Wtl, acc);

#pragma unroll
    for (int mt = 0; mt < 2; ++mt)
#pragma unroll
        for (int r = 0; r < 4; ++r) {
            int row = nb + mt * 16 + quad * 4 + r;
#pragma unroll
            for (int nt = 0; nt < 4; ++nt) {
                int col = wave * 64 + nt * 16 + l16;
                Fout[(size_t)row * EMB + col] = acc[mt][nt][r];
            }
        }
}

// ---------------- fused tail: agg(Fin)+b2 -> LDS -> 3 MLP layers -> out ----------------

__global__ __launch_bounds__(256) void k_mlp_fused(
    const float* __restrict__ Fin,
    const int* __restrict__ ro2, const int* __restrict__ csr_src,
    const float* __restrict__ csr_norm, const float* __restrict__ dinv,
    const float* __restrict__ bagg,
    const unsigned short* __restrict__ Wth3, const unsigned short* __restrict__ Wtl3,
    const float* __restrict__ b3,
    const unsigned short* __restrict__ Wth4, const unsigned short* __restrict__ Wtl4,
    const float* __restrict__ b4,
    const unsigned short* __restrict__ Wth5, const unsigned short* __restrict__ Wtl5,
    const float* __restrict__ b5,
    float* __restrict__ out)
{
    __shared__ float S[MROWS][SROW];
    int tid  = threadIdx.x;
    int lane = tid & 63, wave = tid >> 6;
    int quad = lane >> 4, l16 = lane & 15;
    int nb   = blockIdx.x * MROWS;

    agg_to_lds_chunked(S, nb, wave, lane, tid, blockIdx.x,
                       Fin, ro2, csr_src, csr_norm, dinv, bagg, 0);
    __syncthreads();

    f32x4 acc[2][4];

    // mlp1: relu(S @ W3 + b3) -> S
    gemm_layer(S, wave, quad, l16, Wth3, Wtl3, acc);
    __syncthreads();   // all reads of S done before overwrite
#pragma unroll
    for (int mt = 0; mt < 2; ++mt)
#pragma unroll
        for (int r = 0; r < 4; ++r) {
            int row = mt * 16 + quad * 4 + r;
#pragma unroll
            for (int nt = 0; nt < 4; ++nt) {
                int col = wave * 64 + nt * 16 + l16;
                S[row][col] = fmaxf(acc[mt][nt][r] + b3[col], 0.f);
            }
        }
    __syncthreads();

    // mlp2: relu(S @ W4 + b4) -> S
    gemm_layer(S, wave, quad, l16, Wth4, Wtl4, acc);
    __syncthreads();
#pragma unroll
    for (int mt = 0; mt < 2; ++mt)
#pragma unroll
        for (int r = 0; r < 4; ++r) {
            int row = mt * 16 + quad * 4 + r;
#pragma unroll
            for (int nt = 0; nt < 4; ++nt) {
                int col = wave * 64 + nt * 16 + l16;
                S[row][col] = fmaxf(acc[mt][nt][r] + b4[col], 0.f);
            }
        }
    __syncthreads();

    // mlp3: S @ W5 + b5 -> global out
    gemm_layer(S, wave, quad, l16, Wth5, Wtl5, acc);
#pragma unroll
    for (int mt = 0; mt < 2; ++mt)
#pragma unroll
        for (int r = 0; r < 4; ++r) {
            int row = nb + mt * 16 + quad * 4 + r;
#pragma unroll
            for (int nt = 0; nt < 4; ++nt) {
                int col = wave * 64 + nt * 16 + l16;
                out[(size_t)row * EMB + col] = acc[mt][nt][r] + b5[col];
            }
        }
}

// ---------------- launch (9 dispatches) ----------------

extern "C" void kernel_launch(void* const* d_in, const int* in_sizes, int n_in,
                              void* d_out, int out_size, void* d_ws, size_t ws_size,
                              hipStream_t stream) {
    const float* x  = (const float*)d_in[0];
    const int*   ei = (const int*)d_in[1];
    const int* src = ei;
    const int* dst = ei + N_EDGES;

    const float* w[6] = {
        (const float*)d_in[2], (const float*)d_in[4], (const float*)d_in[6],
        (const float*)d_in[8], (const float*)d_in[10], (const float*)d_in[12] };
    const float* b[6] = {
        (const float*)d_in[3], (const float*)d_in[5], (const float*)d_in[7],
        (const float*)d_in[9], (const float*)d_in[11], (const float*)d_in[13] };

    char* wsp = (char*)d_ws;
    auto alloc = [&](size_t bytes) {
        char* p = wsp; wsp += (bytes + 255) & ~(size_t)255; return p;
    };
    int*   deg2     = (int*)alloc((size_t)N_NODES * NC * 4);
    int*   cursor2  = (int*)alloc((size_t)N_NODES * NC * 4);
    int*   ro2      = (int*)alloc(((size_t)N_NODES * NC + 1) * 4);
    int*   csr_src  = (int*)alloc(N_EDGES * 4);
    float* csr_norm = (float*)alloc(N_EDGES * 4);
    float* dinv     = (float*)alloc(N_NODES * 4);
    unsigned short* wth[6];
    unsigned short* wtl[6];
    wth[0] = (unsigned short*)alloc(EMB * KPAD0 * 2);
    wtl[0] = (unsigned short*)alloc(EMB * KPAD0 * 2);
    for (int i = 1; i < 6; ++i) {
        wth[i] = (unsigned short*)alloc(EMB * EMB * 2);
        wtl[i] = (unsigned short*)alloc(EMB * EMB * 2);
    }
    float* FA = (float*)alloc((size_t)N_NODES * EMB * 4);   // ws f32 buffer
    float* FB = (float*)d_out;                               // d_out doubles as scratch

    const int NB_E = (N_EDGES + 255) / 256;               // 1250
    const int NB_I = (N_NODES * NC + 255) / 256;          // 782
    const int MB   = N_NODES / MROWS;                     // 625

    // chunked CSR build
    k_init2<<<NB_I, 256, 0, stream>>>(deg2, cursor2, N_NODES * NC);
    k_deg2<<<NB_E, 256, 0, stream>>>(src, dst, deg2, N_EDGES);
    k_scan2<<<1, 1024, 0, stream>>>(deg2, ro2, dinv);
    k_scatter2<<<NB_E, 256, 0, stream>>>(src, dst, ro2, cursor2, dinv,
                                         csr_src, csr_norm, N_EDGES);

    // weights: transpose + hi/lo split, one dispatch
    WSplitArgs wa;
    for (int i = 0; i < 6; ++i) { wa.w[i] = w[i]; wa.th[i] = wth[i]; wa.tl[i] = wtl[i]; }
    k_wsplit_all<<<320, 256, 0, stream>>>(wa);

    // conv0 gemm: x @ W0 -> FA
    k_gemm0<<<MB, 256, 0, stream>>>(x, wth[0], wtl[0], FA);
    // conv1: agg(FA)+b0,relu -> @W1 -> FB
    k_conv_fused<<<MB, 256, 0, stream>>>(FA, ro2, csr_src, csr_norm, dinv,
                                         b[0], wth[1], wtl[1], FB);
    // conv2: agg(FB)+b1,relu -> @W2 -> FA
    k_conv_fused<<<MB, 256, 0, stream>>>(FB, ro2, csr_src, csr_norm, dinv,
                                         b[1], wth[2], wtl[2], FA);
    // tail: agg(FA)+b2 -> mlp1(relu) -> mlp2(relu) -> mlp3 -> d_out
    k_mlp_fused<<<MB, 256, 0, stream>>>(FA, ro2, csr_src, csr_norm, dinv,
                                        b[2],
                                        wth[3], wtl[3], b[3],
                                        wth[4], wtl[4], b[4],
                                        wth[5], wtl[5], b[5],
                                        FB);
}

// Round 3
// 549.136 us; speedup vs baseline: 1.0921x; 1.0921x over previous
//
#include <hip/hip_runtime.h>
#include <stdint.h>

#define N_NODES 20000
#define N_EDGES 320000
#define EMB     256
#define D_IN    300
#define KPAD0   320   // D_IN padded to multiple of 32
#define SROW    260   // LDS row stride in floats (multiple of 4 -> 16B-aligned float4)
#define MROWS   32    // GEMM block M-tile

// src-chunk bucketing: 2048 rows = 2MB of F, L2-sized. Buckets only ORDER the
// edge list per node (locality); aggregation runs one flat loop per node.
#define CHUNK_BITS 11
#define NC      10    // ceil(20000/2048)

typedef __attribute__((ext_vector_type(8))) short s16x8;   // 8 bf16 operand (4 VGPRs)
typedef __attribute__((ext_vector_type(4))) float f32x4;

static __device__ __forceinline__ float bf2f(unsigned short u) {
    union { unsigned u; float f; } x; x.u = ((unsigned)u) << 16; return x.f;
}
static __device__ __forceinline__ unsigned short f2bf(float f) {
    union { float f; unsigned u; } x; x.f = f;
    unsigned r = x.u + 0x7fffu + ((x.u >> 16) & 1u);   // RNE
    return (unsigned short)(r >> 16);
}
// split v = hi + lo (each bf16), |err| <= 2^-18 |v|
static __device__ __forceinline__ void split_bf(float v, unsigned short& h, unsigned short& l) {
    h = f2bf(v);
    l = f2bf(v - bf2f(h));
}
static __device__ __forceinline__ void split8(const float* fv, s16x8& hi, s16x8& lo) {
#pragma unroll
    for (int j = 0; j < 8; ++j) {
        unsigned short h, l;
        split_bf(fv[j], h, l);
        hi[j] = (short)h; lo[j] = (short)l;
    }
}

// ---------------- chunk-bucketed CSR build (4 dispatches) ----------------

__global__ void k_init2(int* deg2, int* cursor2, int n) {
    int i = blockIdx.x * 256 + threadIdx.x;
    if (i < n) { deg2[i] = 0; cursor2[i] = 0; }
}

__global__ void k_deg2(const int* __restrict__ src, const int* __restrict__ dst,
                       int* __restrict__ deg2, int e) {
    int i = blockIdx.x * 256 + threadIdx.x;
    if (i < e) {
        int s = src[i], d = dst[i];
        atomicAdd(&deg2[d * NC + (s >> CHUNK_BITS)], 1);
    }
}

// single-block: exclusive scan over flat deg2[n*NC] -> ro2[0..n*NC], plus dinv
__global__ void k_scan2(const int* __restrict__ deg2, int* __restrict__ ro2,
                        float* __restrict__ dinv) {
    __shared__ int sums[1024];
    int tid = threadIdx.x;
    const int NPT = 20;                       // nodes per thread (1024*20 >= 20000)
    int n0 = tid * NPT; if (n0 > N_NODES) n0 = N_NODES;
    int n1 = n0 + NPT;  if (n1 > N_NODES) n1 = N_NODES;
    int s = 0;
    for (int n = n0; n < n1; ++n) {
        int rs = 0;
#pragma unroll
        for (int c = 0; c < NC; ++c) rs += deg2[n * NC + c];
        dinv[n] = rsqrtf((float)(rs + 1));    // +1 self-loop
        s += rs;
    }
    sums[tid] = s;
    __syncthreads();
    for (int off = 1; off < 1024; off <<= 1) {
        int v = (tid >= off) ? sums[tid - off] : 0;
        __syncthreads();
        sums[tid] += v;
        __syncthreads();
    }
    int excl = (tid == 0) ? 0 : sums[tid - 1];
    for (int n = n0; n < n1; ++n)
#pragma unroll
        for (int c = 0; c < NC; ++c) {
            ro2[n * NC + c] = excl;
            excl += deg2[n * NC + c];
        }
    if (tid == 1023) ro2[N_NODES * NC] = sums[1023];
}

// packed edge record: {src, norm bits} -> one 8B load per edge
__global__ void k_scatter2(const int* __restrict__ src, const int* __restrict__ dst,
                           const int* __restrict__ ro2, int* __restrict__ cursor2,
                           const float* __restrict__ dinv,
                           int2* __restrict__ csr, int e) {
    int i = blockIdx.x * 256 + threadIdx.x;
    if (i >= e) return;
    int s = src[i], d = dst[i];
    int slot = d * NC + (s >> CHUNK_BITS);
    int pos = ro2[slot] + atomicAdd(&cursor2[slot], 1);
    float nrm = dinv[s] * dinv[d];
    csr[pos] = make_int2(s, __float_as_int(nrm));
}

// ---------------- batched weight transpose+split (1 dispatch for all 6) ----------------

struct WSplitArgs {
    const float* w[6];
    unsigned short* th[6];
    unsigned short* tl[6];
};

__global__ void k_wsplit_all(WSplitArgs a) {
#pragma unroll
    for (int l = 0; l < 6; ++l) {
        const int K    = (l == 0) ? D_IN  : EMB;
        const int Kpad = (l == 0) ? KPAD0 : EMB;
        const int tot  = EMB * Kpad;
        for (int idx = blockIdx.x * 256 + threadIdx.x; idx < tot; idx += gridDim.x * 256) {
            int n = idx / Kpad, k = idx - n * Kpad;
            float v = (k < K) ? a.w[l][k * EMB + n] : 0.f;
            unsigned short h, lo;
            split_bf(v, h, lo);
            a.th[l][idx] = h; a.tl[l][idx] = lo;
        }
    }
}

// ---------------- dedicated aggregation: wave-per-node, flat chunk-ordered loop ----------------
// G[node] = (relu?)( bias + dinv^2*F[node] + sum_j norm_j * F[src_j] )
// Edge list per node is bucketed by src-chunk (2MB) => all concurrent waves sweep
// the same src window => gathers hit L2.

__global__ __launch_bounds__(256) void k_agg(
    const float* __restrict__ Fin,
    const int* __restrict__ ro2,
    const int2* __restrict__ csr,
    const float* __restrict__ dinv,
    const float* __restrict__ bagg,
    float* __restrict__ G, int relu)
{
    int tid  = threadIdx.x;
    int lane = tid & 63, wave = tid >> 6;
    int node = blockIdx.x * 4 + wave;
    if (node >= N_NODES) return;

    const float4* F4 = (const float4*)Fin;
    float4 bb = *(const float4*)(bagg + lane * 4);

    float dv = dinv[node];
    float ws = dv * dv;
    float4 sv = F4[(size_t)node * 64 + lane];
    float a0 = bb.x + ws * sv.x;
    float a1 = bb.y + ws * sv.y;
    float a2 = bb.z + ws * sv.z;
    float a3 = bb.w + ws * sv.w;

    int j  = ro2[node * NC];
    int je = ro2[node * NC + NC];
    for (; j + 3 < je; j += 4) {
        int2 p0 = csr[j],     p1 = csr[j + 1];
        int2 p2 = csr[j + 2], p3 = csr[j + 3];
        float4 v0 = F4[(size_t)p0.x * 64 + lane];
        float4 v1 = F4[(size_t)p1.x * 64 + lane];
        float4 v2 = F4[(size_t)p2.x * 64 + lane];
        float4 v3 = F4[(size_t)p3.x * 64 + lane];
        float w0 = __int_as_float(p0.y), w1 = __int_as_float(p1.y);
        float w2 = __int_as_float(p2.y), w3 = __int_as_float(p3.y);
        a0 += w0 * v0.x + w1 * v1.x + w2 * v2.x + w3 * v3.x;
        a1 += w0 * v0.y + w1 * v1.y + w2 * v2.y + w3 * v3.y;
        a2 += w0 * v0.z + w1 * v1.z + w2 * v2.z + w3 * v3.z;
        a3 += w0 * v0.w + w1 * v1.w + w2 * v2.w + w3 * v3.w;
    }
    for (; j < je; ++j) {
        int2 p = csr[j];
        float w = __int_as_float(p.y);
        float4 v = F4[(size_t)p.x * 64 + lane];
        a0 += w * v.x; a1 += w * v.y; a2 += w * v.z; a3 += w * v.w;
    }

    if (relu) {
        a0 = fmaxf(a0, 0.f); a1 = fmaxf(a1, 0.f);
        a2 = fmaxf(a2, 0.f); a3 = fmaxf(a3, 0.f);
    }
    float4 o; o.x = a0; o.y = a1; o.z = a2; o.w = a3;
    *(float4*)(G + (size_t)node * EMB + lane * 4) = o;
}

// ---------------- conv0 GEMM: C[M,256] = x[M,300] @ W0 ----------------
// block = 4 waves; 32 rows x 256 cols; MFMA 16x16x32 bf16, split hi/lo.

__global__ __launch_bounds__(256) void k_gemm0(
    const float* __restrict__ A,
    const unsigned short* __restrict__ Wth,
    const unsigned short* __restrict__ Wtl,
    float* __restrict__ C)
{
    int tid  = threadIdx.x;
    int lane = tid & 63, wave = tid >> 6;
    int quad = lane >> 4, l16 = lane & 15;
    int m_base = blockIdx.x * 32;

    f32x4 acc[2][4];
#pragma unroll
    for (int mt = 0; mt < 2; ++mt)
#pragma unroll
        for (int nt = 0; nt < 4; ++nt) acc[mt][nt] = (f32x4){0.f, 0.f, 0.f, 0.f};

    for (int ks = 0; ks < KPAD0 / 32; ++ks) {
        int k0 = ks * 32 + quad * 8;
        s16x8 ah[2], al[2], bh[4], bl[4];
#pragma unroll
        for (int nt = 0; nt < 4; ++nt) {
            int nn = wave * 64 + nt * 16 + l16;
            bh[nt] = *(const s16x8*)(Wth + (size_t)nn * KPAD0 + k0);
            bl[nt] = *(const s16x8*)(Wtl + (size_t)nn * KPAD0 + k0);
        }
#pragma unroll
        for (int mt = 0; mt < 2; ++mt) {
            int row = m_base + mt * 16 + l16;
            const float* ar = A + (size_t)row * D_IN;
            float fv[8];
            if (row == N_NODES - 1 && k0 + 8 > D_IN) {
#pragma unroll
                for (int j = 0; j < 8; ++j) {
                    int kk = k0 + j;
                    fv[j] = (kk < D_IN) ? ar[kk] : 0.f;
                }
            } else {
                // k past 299 reads next row's data; harmless: Wt zero-padded there.
                *(float4*)(fv)     = *(const float4*)(ar + k0);
                *(float4*)(fv + 4) = *(const float4*)(ar + k0 + 4);
            }
            split8(fv, ah[mt], al[mt]);
        }
#pragma unroll
        for (int mt = 0; mt < 2; ++mt)
#pragma unroll
            for (int nt = 0; nt < 4; ++nt) {
                acc[mt][nt] = __builtin_amdgcn_mfma_f32_16x16x32_bf16(ah[mt], bh[nt], acc[mt][nt], 0, 0, 0);
                acc[mt][nt] = __builtin_amdgcn_mfma_f32_16x16x32_bf16(ah[mt], bl[nt], acc[mt][nt], 0, 0, 0);
                acc[mt][nt] = __builtin_amdgcn_mfma_f32_16x16x32_bf16(al[mt], bh[nt], acc[mt][nt], 0, 0, 0);
            }
    }

#pragma unroll
    for (int mt = 0; mt < 2; ++mt)
#pragma unroll
        for (int r = 0; r < 4; ++r) {
            int row = m_base + mt * 16 + quad * 4 + r;
#pragma unroll
            for (int nt = 0; nt < 4; ++nt) {
                int col = wave * 64 + nt * 16 + l16;
                C[(size_t)row * EMB + col] = acc[mt][nt][r];
            }
        }
}

// ---------------- K=256 GEMM: C[M,256] = G[M,256] @ W (no epilogue) ----------------

__global__ __launch_bounds__(256) void k_gemm256(
    const float* __restrict__ A,
    const unsigned short* __restrict__ Wth,
    const unsigned short* __restrict__ Wtl,
    float* __restrict__ C)
{
    int tid  = threadIdx.x;
    int lane = tid & 63, wave = tid >> 6;
    int quad = lane >> 4, l16 = lane & 15;
    int m_base = blockIdx.x * 32;

    f32x4 acc[2][4];
#pragma unroll
    for (int mt = 0; mt < 2; ++mt)
#pragma unroll
        for (int nt = 0; nt < 4; ++nt) acc[mt][nt] = (f32x4){0.f, 0.f, 0.f, 0.f};

    for (int ks = 0; ks < EMB / 32; ++ks) {
        int k0 = ks * 32 + quad * 8;
        s16x8 ah[2], al[2], bh[4], bl[4];
#pragma unroll
        for (int nt = 0; nt < 4; ++nt) {
            int nn = wave * 64 + nt * 16 + l16;
            bh[nt] = *(const s16x8*)(Wth + (size_t)nn * EMB + k0);
            bl[nt] = *(const s16x8*)(Wtl + (size_t)nn * EMB + k0);
        }
#pragma unroll
        for (int mt = 0; mt < 2; ++mt) {
            const float* ar = A + (size_t)(m_base + mt * 16 + l16) * EMB;
            float fv[8];
            *(float4*)(fv)     = *(const float4*)(ar + k0);
            *(float4*)(fv + 4) = *(const float4*)(ar + k0 + 4);
            split8(fv, ah[mt], al[mt]);
        }
#pragma unroll
        for (int mt = 0; mt < 2; ++mt)
#pragma unroll
            for (int nt = 0; nt < 4; ++nt) {
                acc[mt][nt] = __builtin_amdgcn_mfma_f32_16x16x32_bf16(ah[mt], bh[nt], acc[mt][nt], 0, 0, 0);
                acc[mt][nt] = __builtin_amdgcn_mfma_f32_16x16x32_bf16(ah[mt], bl[nt], acc[mt][nt], 0, 0, 0);
                acc[mt][nt] = __builtin_amdgcn_mfma_f32_16x16x32_bf16(al[mt], bh[nt], acc[mt][nt], 0, 0, 0);
            }
    }

#pragma unroll
    for (int mt = 0; mt < 2; ++mt)
#pragma unroll
        for (int r = 0; r < 4; ++r) {
            int row = m_base + mt * 16 + quad * 4 + r;
#pragma unroll
            for (int nt = 0; nt < 4; ++nt) {
                int col = wave * 64 + nt * 16 + l16;
                C[(size_t)row * EMB + col] = acc[mt][nt][r];
            }
        }
}

// ---------------- MLP GEMM layer from LDS ----------------

static __device__ __forceinline__ void gemm_layer(
    const float (*S)[SROW], int wave, int quad, int l16,
    const unsigned short* __restrict__ Wth,
    const unsigned short* __restrict__ Wtl,
    f32x4 acc[2][4])
{
#pragma unroll
    for (int mt = 0; mt < 2; ++mt)
#pragma unroll
        for (int nt = 0; nt < 4; ++nt) acc[mt][nt] = (f32x4){0.f, 0.f, 0.f, 0.f};

    for (int ks = 0; ks < EMB / 32; ++ks) {
        int k0 = ks * 32 + quad * 8;
        s16x8 ah[2], al[2], bh[4], bl[4];
#pragma unroll
        for (int nt = 0; nt < 4; ++nt) {
            int nn = wave * 64 + nt * 16 + l16;
            bh[nt] = *(const s16x8*)(Wth + (size_t)nn * EMB + k0);
            bl[nt] = *(const s16x8*)(Wtl + (size_t)nn * EMB + k0);
        }
#pragma unroll
        for (int mt = 0; mt < 2; ++mt) {
            float fv[8];
            *(float4*)(fv)     = *(const float4*)&S[mt * 16 + l16][k0];
            *(float4*)(fv + 4) = *(const float4*)&S[mt * 16 + l16][k0 + 4];
            split8(fv, ah[mt], al[mt]);
        }
#pragma unroll
        for (int mt = 0; mt < 2; ++mt)
#pragma unroll
            for (int nt = 0; nt < 4; ++nt) {
                acc[mt][nt] = __builtin_amdgcn_mfma_f32_16x16x32_bf16(ah[mt], bh[nt], acc[mt][nt], 0, 0, 0);
                acc[mt][nt] = __builtin_amdgcn_mfma_f32_16x16x32_bf16(ah[mt], bl[nt], acc[mt][nt], 0, 0, 0);
                acc[mt][nt] = __builtin_amdgcn_mfma_f32_16x16x32_bf16(al[mt], bh[nt], acc[mt][nt], 0, 0, 0);
            }
    }
}

// ---------------- MLP tail: G -> LDS -> 3 GEMM layers -> out ----------------

__global__ __launch_bounds__(256) void k_mlp3(
    const float* __restrict__ G,
    const unsigned short* __restrict__ Wth3, const unsigned short* __restrict__ Wtl3,
    const float* __restrict__ b3,
    const unsigned short* __restrict__ Wth4, const unsigned short* __restrict__ Wtl4,
    const float* __restrict__ b4,
    const unsigned short* __restrict__ Wth5, const unsigned short* __restrict__ Wtl5,
    const float* __restrict__ b5,
    float* __restrict__ out)
{
    __shared__ float S[MROWS][SROW];
    int tid  = threadIdx.x;
    int lane = tid & 63, wave = tid >> 6;
    int quad = lane >> 4, l16 = lane & 15;
    int nb   = blockIdx.x * MROWS;

    // copy 32 rows of G into S
    for (int u = tid; u < 32 * 64; u += 256) {
        int r = u >> 6, c = u & 63;
        *(float4*)&S[r][c * 4] = *(const float4*)(G + (size_t)(nb + r) * EMB + c * 4);
    }
    __syncthreads();

    f32x4 acc[2][4];

    // mlp1: relu(S @ W3 + b3) -> S
    gemm_layer(S, wave, quad, l16, Wth3, Wtl3, acc);
    __syncthreads();
#pragma unroll
    for (int mt = 0; mt < 2; ++mt)
#pragma unroll
        for (int r = 0; r < 4; ++r) {
            int row = mt * 16 + quad * 4 + r;
#pragma unroll
            for (int nt = 0; nt < 4; ++nt) {
                int col = wave * 64 + nt * 16 + l16;
                S[row][col] = fmaxf(acc[mt][nt][r] + b3[col], 0.f);
            }
        }
    __syncthreads();

    // mlp2: relu(S @ W4 + b4) -> S
    gemm_layer(S, wave, quad, l16, Wth4, Wtl4, acc);
    __syncthreads();
#pragma unroll
    for (int mt = 0; mt < 2; ++mt)
#pragma unroll
        for (int r = 0; r < 4; ++r) {
            int row = mt * 16 + quad * 4 + r;
#pragma unroll
            for (int nt = 0; nt < 4; ++nt) {
                int col = wave * 64 + nt * 16 + l16;
                S[row][col] = fmaxf(acc[mt][nt][r] + b4[col], 0.f);
            }
        }
    __syncthreads();

    // mlp3: S @ W5 + b5 -> global out
    gemm_layer(S, wave, quad, l16, Wth5, Wtl5, acc);
#pragma unroll
    for (int mt = 0; mt < 2; ++mt)
#pragma unroll
        for (int r = 0; r < 4; ++r) {
            int row = nb + mt * 16 + quad * 4 + r;
#pragma unroll
            for (int nt = 0; nt < 4; ++nt) {
                int col = wave * 64 + nt * 16 + l16;
                out[(size_t)row * EMB + col] = acc[mt][nt][r] + b5[col];
            }
        }
}

// ---------------- launch (12 dispatches) ----------------

extern "C" void kernel_launch(void* const* d_in, const int* in_sizes, int n_in,
                              void* d_out, int out_size, void* d_ws, size_t ws_size,
                              hipStream_t stream) {
    const float* x  = (const float*)d_in[0];
    const int*   ei = (const int*)d_in[1];
    const int* src = ei;
    const int* dst = ei + N_EDGES;

    const float* w[6] = {
        (const float*)d_in[2], (const float*)d_in[4], (const float*)d_in[6],
        (const float*)d_in[8], (const float*)d_in[10], (const float*)d_in[12] };
    const float* b[6] = {
        (const float*)d_in[3], (const float*)d_in[5], (const float*)d_in[7],
        (const float*)d_in[9], (const float*)d_in[11], (const float*)d_in[13] };

    char* wsp = (char*)d_ws;
    auto alloc = [&](size_t bytes) {
        char* p = wsp; wsp += (bytes + 255) & ~(size_t)255; return p;
    };
    int*   deg2     = (int*)alloc((size_t)N_NODES * NC * 4);
    int*   cursor2  = (int*)alloc((size_t)N_NODES * NC * 4);
    int*   ro2      = (int*)alloc(((size_t)N_NODES * NC + 1) * 4);
    int2*  csr      = (int2*)alloc((size_t)N_EDGES * 8);
    float* dinv     = (float*)alloc(N_NODES * 4);
    unsigned short* wth[6];
    unsigned short* wtl[6];
    wth[0] = (unsigned short*)alloc(EMB * KPAD0 * 2);
    wtl[0] = (unsigned short*)alloc(EMB * KPAD0 * 2);
    for (int i = 1; i < 6; ++i) {
        wth[i] = (unsigned short*)alloc(EMB * EMB * 2);
        wtl[i] = (unsigned short*)alloc(EMB * EMB * 2);
    }
    float* FA = (float*)alloc((size_t)N_NODES * EMB * 4);   // feature buffer
    float* G  = (float*)alloc((size_t)N_NODES * EMB * 4);   // aggregated buffer
    float* FB = (float*)d_out;                               // d_out doubles as scratch

    const int NB_E = (N_EDGES + 255) / 256;               // 1250
    const int NB_I = (N_NODES * NC + 255) / 256;          // 782
    const int MB   = N_NODES / MROWS;                     // 625
    const int AB   = (N_NODES + 3) / 4;                   // 5000 (wave-per-node)

    // chunk-bucketed CSR build
    k_init2<<<NB_I, 256, 0, stream>>>(deg2, cursor2, N_NODES * NC);
    k_deg2<<<NB_E, 256, 0, stream>>>(src, dst, deg2, N_EDGES);
    k_scan2<<<1, 1024, 0, stream>>>(deg2, ro2, dinv);
    k_scatter2<<<NB_E, 256, 0, stream>>>(src, dst, ro2, cursor2, dinv, csr, N_EDGES);

    // weights: transpose + hi/lo split
    WSplitArgs wa;
    for (int i = 0; i < 6; ++i) { wa.w[i] = w[i]; wa.th[i] = wth[i]; wa.tl[i] = wtl[i]; }
    k_wsplit_all<<<320, 256, 0, stream>>>(wa);

    // conv0 gemm: x @ W0 -> FA
    k_gemm0<<<MB, 256, 0, stream>>>(x, wth[0], wtl[0], FA);

    // conv1: agg(FA)+b0,relu -> G ; G @ W1 -> FB
    k_agg<<<AB, 256, 0, stream>>>(FA, ro2, csr, dinv, b[0], G, 1);
    k_gemm256<<<MB, 256, 0, stream>>>(G, wth[1], wtl[1], FB);

    // conv2: agg(FB)+b1,relu -> G ; G @ W2 -> FA
    k_agg<<<AB, 256, 0, stream>>>(FB, ro2, csr, dinv, b[1], G, 1);
    k_gemm256<<<MB, 256, 0, stream>>>(G, wth[2], wtl[2], FA);

    // tail: agg(FA)+b2 -> G ; G -> mlp1(relu) -> mlp2(relu) -> mlp3 -> out
    k_agg<<<AB, 256, 0, stream>>>(FA, ro2, csr, dinv, b[2], G, 0);
    k_mlp3<<<MB, 256, 0, stream>>>(G,
                                   wth[3], wtl[3], b[3],
                                   wth[4], wtl[4], b[4],
                                   wth[5], wtl[5], b[5],
                                   FB);
}

// Round 4
// 450.225 us; speedup vs baseline: 1.3320x; 1.2197x over previous
//
#include <hip/hip_runtime.h>
#include <stdint.h>

#define N_NODES 20000
#define N_EDGES 320000
#define EMB     256
#define D_IN    300
#define KPAD0   320   // D_IN padded to multiple of 32
#define SROW    260   // LDS row stride in floats (multiple of 4 -> 16B-aligned float4)
#define MROWS   32    // GEMM block M-tile

// src-chunk bucketing: 2048 rows = 2MB of F, L2-sized. Buckets only ORDER the
// edge list per node (locality); aggregation runs one flat loop per node.
#define CHUNK_BITS 11
#define NC      10    // ceil(20000/2048)

// multi-block scan geometry
#define SCAN_L    (N_NODES * NC)          // 200000
#define SCAN_TPB  256
#define SCAN_VPT  4                       // elements per thread
#define SCAN_TILE (SCAN_TPB * SCAN_VPT)   // 1024
#define SCAN_NBLK ((SCAN_L + SCAN_TILE - 1) / SCAN_TILE)  // 196 (<= 256)

typedef __attribute__((ext_vector_type(8))) short s16x8;   // 8 bf16 operand (4 VGPRs)
typedef __attribute__((ext_vector_type(4))) float f32x4;

static __device__ __forceinline__ float bf2f(unsigned short u) {
    union { unsigned u; float f; } x; x.u = ((unsigned)u) << 16; return x.f;
}
static __device__ __forceinline__ unsigned short f2bf(float f) {
    union { float f; unsigned u; } x; x.f = f;
    unsigned r = x.u + 0x7fffu + ((x.u >> 16) & 1u);   // RNE
    return (unsigned short)(r >> 16);
}
// split v = hi + lo (each bf16), |err| <= 2^-18 |v|
static __device__ __forceinline__ void split_bf(float v, unsigned short& h, unsigned short& l) {
    h = f2bf(v);
    l = f2bf(v - bf2f(h));
}
static __device__ __forceinline__ void split8(const float* fv, s16x8& hi, s16x8& lo) {
#pragma unroll
    for (int j = 0; j < 8; ++j) {
        unsigned short h, l;
        split_bf(fv[j], h, l);
        hi[j] = (short)h; lo[j] = (short)l;
    }
}

// ---------------- chunk-bucketed CSR build ----------------

__global__ void k_init2(int* deg2, int* cursor2, int n) {
    int i = blockIdx.x * 256 + threadIdx.x;
    if (i < n) { deg2[i] = 0; cursor2[i] = 0; }
}

__global__ void k_deg2(const int* __restrict__ src, const int* __restrict__ dst,
                       int* __restrict__ deg2, int e) {
    int i = blockIdx.x * 256 + threadIdx.x;
    if (i < e) {
        int s = src[i], d = dst[i];
        atomicAdd(&deg2[d * NC + (s >> CHUNK_BITS)], 1);
    }
}

// --- 3-phase multi-block exclusive scan over deg2[SCAN_L] -> ro2[0..SCAN_L] ---

__global__ __launch_bounds__(SCAN_TPB) void k_scan_part(
    const int* __restrict__ deg2, int* __restrict__ part)
{
    __shared__ int red[SCAN_TPB];
    int tid  = threadIdx.x;
    int base = blockIdx.x * SCAN_TILE + tid * SCAN_VPT;
    int s = 0;
#pragma unroll
    for (int u = 0; u < SCAN_VPT; ++u) {
        int i = base + u;
        s += (i < SCAN_L) ? deg2[i] : 0;
    }
    red[tid] = s;
    __syncthreads();
    for (int off = SCAN_TPB / 2; off > 0; off >>= 1) {
        if (tid < off) red[tid] += red[tid + off];
        __syncthreads();
    }
    if (tid == 0) part[blockIdx.x] = red[0];
}

// single small block: convert partial sums -> exclusive block offsets (in place)
__global__ __launch_bounds__(SCAN_TPB) void k_scan_root(int* part) {
    __shared__ int sh[SCAN_TPB];
    int tid = threadIdx.x;
    int v = (tid < SCAN_NBLK) ? part[tid] : 0;
    sh[tid] = v;
    __syncthreads();
    for (int off = 1; off < SCAN_TPB; off <<= 1) {
        int t = (tid >= off) ? sh[tid - off] : 0;
        __syncthreads();
        sh[tid] += t;
        __syncthreads();
    }
    if (tid < SCAN_NBLK) part[tid] = (tid == 0) ? 0 : sh[tid - 1];
}

__global__ __launch_bounds__(SCAN_TPB) void k_scan_write(
    const int* __restrict__ deg2, const int* __restrict__ part,
    int* __restrict__ ro2)
{
    __shared__ int red[SCAN_TPB];
    int tid  = threadIdx.x;
    int base = blockIdx.x * SCAN_TILE + tid * SCAN_VPT;
    int v[SCAN_VPT];
    int s = 0;
#pragma unroll
    for (int u = 0; u < SCAN_VPT; ++u) {
        int i = base + u;
        v[u] = (i < SCAN_L) ? deg2[i] : 0;
        s += v[u];
    }
    red[tid] = s;
    __syncthreads();
    for (int off = 1; off < SCAN_TPB; off <<= 1) {
        int t = (tid >= off) ? red[tid - off] : 0;
        __syncthreads();
        red[tid] += t;
        __syncthreads();
    }
    int excl = part[blockIdx.x] + ((tid == 0) ? 0 : red[tid - 1]);
#pragma unroll
    for (int u = 0; u < SCAN_VPT; ++u) {
        int i = base + u;
        if (i < SCAN_L) {
            ro2[i] = excl;
            excl += v[u];
            if (i == SCAN_L - 1) ro2[SCAN_L] = excl;   // total edges
        }
    }
}

__global__ void k_dinv(const int* __restrict__ ro2, float* __restrict__ dinv) {
    int n = blockIdx.x * 256 + threadIdx.x;
    if (n < N_NODES) {
        int d = ro2[(n + 1) * NC] - ro2[n * NC];
        dinv[n] = rsqrtf((float)(d + 1));   // +1 self-loop
    }
}

// packed edge record: {src, norm bits} -> one 8B load per edge
__global__ void k_scatter2(const int* __restrict__ src, const int* __restrict__ dst,
                           const int* __restrict__ ro2, int* __restrict__ cursor2,
                           const float* __restrict__ dinv,
                           int2* __restrict__ csr, int e) {
    int i = blockIdx.x * 256 + threadIdx.x;
    if (i >= e) return;
    int s = src[i], d = dst[i];
    int slot = d * NC + (s >> CHUNK_BITS);
    int pos = ro2[slot] + atomicAdd(&cursor2[slot], 1);
    float nrm = dinv[s] * dinv[d];
    csr[pos] = make_int2(s, __float_as_int(nrm));
}

// ---------------- batched weight transpose+split (1 dispatch for all 6) ----------------

struct WSplitArgs {
    const float* w[6];
    unsigned short* th[6];
    unsigned short* tl[6];
};

__global__ void k_wsplit_all(WSplitArgs a) {
#pragma unroll
    for (int l = 0; l < 6; ++l) {
        const int K    = (l == 0) ? D_IN  : EMB;
        const int Kpad = (l == 0) ? KPAD0 : EMB;
        const int tot  = EMB * Kpad;
        for (int idx = blockIdx.x * 256 + threadIdx.x; idx < tot; idx += gridDim.x * 256) {
            int n = idx / Kpad, k = idx - n * Kpad;
            float v = (k < K) ? a.w[l][k * EMB + n] : 0.f;
            unsigned short h, lo;
            split_bf(v, h, lo);
            a.th[l][idx] = h; a.tl[l][idx] = lo;
        }
    }
}

// ---------------- dedicated aggregation: wave-per-node, flat chunk-ordered loop ----------------
// G[node] = (relu?)( bias + dinv^2*F[node] + sum_j norm_j * F[src_j] )
// Edge list per node is bucketed by src-chunk (2MB) => all concurrent waves sweep
// the same src window => gathers hit L2.

__global__ __launch_bounds__(256) void k_agg(
    const float* __restrict__ Fin,
    const int* __restrict__ ro2,
    const int2* __restrict__ csr,
    const float* __restrict__ dinv,
    const float* __restrict__ bagg,
    float* __restrict__ G, int relu)
{
    int tid  = threadIdx.x;
    int lane = tid & 63, wave = tid >> 6;
    int node = blockIdx.x * 4 + wave;
    if (node >= N_NODES) return;

    const float4* F4 = (const float4*)Fin;
    float4 bb = *(const float4*)(bagg + lane * 4);

    float dv = dinv[node];
    float ws = dv * dv;
    float4 sv = F4[(size_t)node * 64 + lane];
    float a0 = bb.x + ws * sv.x;
    float a1 = bb.y + ws * sv.y;
    float a2 = bb.z + ws * sv.z;
    float a3 = bb.w + ws * sv.w;

    int j  = ro2[node * NC];
    int je = ro2[node * NC + NC];
    for (; j + 3 < je; j += 4) {
        int2 p0 = csr[j],     p1 = csr[j + 1];
        int2 p2 = csr[j + 2], p3 = csr[j + 3];
        float4 v0 = F4[(size_t)p0.x * 64 + lane];
        float4 v1 = F4[(size_t)p1.x * 64 + lane];
        float4 v2 = F4[(size_t)p2.x * 64 + lane];
        float4 v3 = F4[(size_t)p3.x * 64 + lane];
        float w0 = __int_as_float(p0.y), w1 = __int_as_float(p1.y);
        float w2 = __int_as_float(p2.y), w3 = __int_as_float(p3.y);
        a0 += w0 * v0.x + w1 * v1.x + w2 * v2.x + w3 * v3.x;
        a1 += w0 * v0.y + w1 * v1.y + w2 * v2.y + w3 * v3.y;
        a2 += w0 * v0.z + w1 * v1.z + w2 * v2.z + w3 * v3.z;
        a3 += w0 * v0.w + w1 * v1.w + w2 * v2.w + w3 * v3.w;
    }
    for (; j < je; ++j) {
        int2 p = csr[j];
        float w = __int_as_float(p.y);
        float4 v = F4[(size_t)p.x * 64 + lane];
        a0 += w * v.x; a1 += w * v.y; a2 += w * v.z; a3 += w * v.w;
    }

    if (relu) {
        a0 = fmaxf(a0, 0.f); a1 = fmaxf(a1, 0.f);
        a2 = fmaxf(a2, 0.f); a3 = fmaxf(a3, 0.f);
    }
    float4 o; o.x = a0; o.y = a1; o.z = a2; o.w = a3;
    *(float4*)(G + (size_t)node * EMB + lane * 4) = o;
}

// ---------------- conv0 GEMM: C[M,256] = x[M,300] @ W0 ----------------
// block = 4 waves; 32 rows x 256 cols; MFMA 16x16x32 bf16, split hi/lo.

__global__ __launch_bounds__(256) void k_gemm0(
    const float* __restrict__ A,
    const unsigned short* __restrict__ Wth,
    const unsigned short* __restrict__ Wtl,
    float* __restrict__ C)
{
    int tid  = threadIdx.x;
    int lane = tid & 63, wave = tid >> 6;
    int quad = lane >> 4, l16 = lane & 15;
    int m_base = blockIdx.x * 32;

    f32x4 acc[2][4];
#pragma unroll
    for (int mt = 0; mt < 2; ++mt)
#pragma unroll
        for (int nt = 0; nt < 4; ++nt) acc[mt][nt] = (f32x4){0.f, 0.f, 0.f, 0.f};

    for (int ks = 0; ks < KPAD0 / 32; ++ks) {
        int k0 = ks * 32 + quad * 8;
        s16x8 ah[2], al[2], bh[4], bl[4];
#pragma unroll
        for (int nt = 0; nt < 4; ++nt) {
            int nn = wave * 64 + nt * 16 + l16;
            bh[nt] = *(const s16x8*)(Wth + (size_t)nn * KPAD0 + k0);
            bl[nt] = *(const s16x8*)(Wtl + (size_t)nn * KPAD0 + k0);
        }
#pragma unroll
        for (int mt = 0; mt < 2; ++mt) {
            int row = m_base + mt * 16 + l16;
            const float* ar = A + (size_t)row * D_IN;
            float fv[8];
            if (row == N_NODES - 1 && k0 + 8 > D_IN) {
#pragma unroll
                for (int j = 0; j < 8; ++j) {
                    int kk = k0 + j;
                    fv[j] = (kk < D_IN) ? ar[kk] : 0.f;
                }
            } else {
                // k past 299 reads next row's data; harmless: Wt zero-padded there.
                *(float4*)(fv)     = *(const float4*)(ar + k0);
                *(float4*)(fv + 4) = *(const float4*)(ar + k0 + 4);
            }
            split8(fv, ah[mt], al[mt]);
        }
#pragma unroll
        for (int mt = 0; mt < 2; ++mt)
#pragma unroll
            for (int nt = 0; nt < 4; ++nt) {
                acc[mt][nt] = __builtin_amdgcn_mfma_f32_16x16x32_bf16(ah[mt], bh[nt], acc[mt][nt], 0, 0, 0);
                acc[mt][nt] = __builtin_amdgcn_mfma_f32_16x16x32_bf16(ah[mt], bl[nt], acc[mt][nt], 0, 0, 0);
                acc[mt][nt] = __builtin_amdgcn_mfma_f32_16x16x32_bf16(al[mt], bh[nt], acc[mt][nt], 0, 0, 0);
            }
    }

#pragma unroll
    for (int mt = 0; mt < 2; ++mt)
#pragma unroll
        for (int r = 0; r < 4; ++r) {
            int row = m_base + mt * 16 + quad * 4 + r;
#pragma unroll
            for (int nt = 0; nt < 4; ++nt) {
                int col = wave * 64 + nt * 16 + l16;
                C[(size_t)row * EMB + col] = acc[mt][nt][r];
            }
        }
}

// ---------------- K=256 GEMM: C[M,256] = G[M,256] @ W (no epilogue) ----------------

__global__ __launch_bounds__(256) void k_gemm256(
    const float* __restrict__ A,
    const unsigned short* __restrict__ Wth,
    const unsigned short* __restrict__ Wtl,
    float* __restrict__ C)
{
    int tid  = threadIdx.x;
    int lane = tid & 63, wave = tid >> 6;
    int quad = lane >> 4, l16 = lane & 15;
    int m_base = blockIdx.x * 32;

    f32x4 acc[2][4];
#pragma unroll
    for (int mt = 0; mt < 2; ++mt)
#pragma unroll
        for (int nt = 0; nt < 4; ++nt) acc[mt][nt] = (f32x4){0.f, 0.f, 0.f, 0.f};

    for (int ks = 0; ks < EMB / 32; ++ks) {
        int k0 = ks * 32 + quad * 8;
        s16x8 ah[2], al[2], bh[4], bl[4];
#pragma unroll
        for (int nt = 0; nt < 4; ++nt) {
            int nn = wave * 64 + nt * 16 + l16;
            bh[nt] = *(const s16x8*)(Wth + (size_t)nn * EMB + k0);
            bl[nt] = *(const s16x8*)(Wtl + (size_t)nn * EMB + k0);
        }
#pragma unroll
        for (int mt = 0; mt < 2; ++mt) {
            const float* ar = A + (size_t)(m_base + mt * 16 + l16) * EMB;
            float fv[8];
            *(float4*)(fv)     = *(const float4*)(ar + k0);
            *(float4*)(fv + 4) = *(const float4*)(ar + k0 + 4);
            split8(fv, ah[mt], al[mt]);
        }
#pragma unroll
        for (int mt = 0; mt < 2; ++mt)
#pragma unroll
            for (int nt = 0; nt < 4; ++nt) {
                acc[mt][nt] = __builtin_amdgcn_mfma_f32_16x16x32_bf16(ah[mt], bh[nt], acc[mt][nt], 0, 0, 0);
                acc[mt][nt] = __builtin_amdgcn_mfma_f32_16x16x32_bf16(ah[mt], bl[nt], acc[mt][nt], 0, 0, 0);
                acc[mt][nt] = __builtin_amdgcn_mfma_f32_16x16x32_bf16(al[mt], bh[nt], acc[mt][nt], 0, 0, 0);
            }
    }

#pragma unroll
    for (int mt = 0; mt < 2; ++mt)
#pragma unroll
        for (int r = 0; r < 4; ++r) {
            int row = m_base + mt * 16 + quad * 4 + r;
#pragma unroll
            for (int nt = 0; nt < 4; ++nt) {
                int col = wave * 64 + nt * 16 + l16;
                C[(size_t)row * EMB + col] = acc[mt][nt][r];
            }
        }
}

// ---------------- MLP GEMM layer from LDS ----------------

static __device__ __forceinline__ void gemm_layer(
    const float (*S)[SROW], int wave, int quad, int l16,
    const unsigned short* __restrict__ Wth,
    const unsigned short* __restrict__ Wtl,
    f32x4 acc[2][4])
{
#pragma unroll
    for (int mt = 0; mt < 2; ++mt)
#pragma unroll
        for (int nt = 0; nt < 4; ++nt) acc[mt][nt] = (f32x4){0.f, 0.f, 0.f, 0.f};

    for (int ks = 0; ks < EMB / 32; ++ks) {
        int k0 = ks * 32 + quad * 8;
        s16x8 ah[2], al[2], bh[4], bl[4];
#pragma unroll
        for (int nt = 0; nt < 4; ++nt) {
            int nn = wave * 64 + nt * 16 + l16;
            bh[nt] = *(const s16x8*)(Wth + (size_t)nn * EMB + k0);
            bl[nt] = *(const s16x8*)(Wtl + (size_t)nn * EMB + k0);
        }
#pragma unroll
        for (int mt = 0; mt < 2; ++mt) {
            float fv[8];
            *(float4*)(fv)     = *(const float4*)&S[mt * 16 + l16][k0];
            *(float4*)(fv + 4) = *(const float4*)&S[mt * 16 + l16][k0 + 4];
            split8(fv, ah[mt], al[mt]);
        }
#pragma unroll
        for (int mt = 0; mt < 2; ++mt)
#pragma unroll
            for (int nt = 0; nt < 4; ++nt) {
                acc[mt][nt] = __builtin_amdgcn_mfma_f32_16x16x32_bf16(ah[mt], bh[nt], acc[mt][nt], 0, 0, 0);
                acc[mt][nt] = __builtin_amdgcn_mfma_f32_16x16x32_bf16(ah[mt], bl[nt], acc[mt][nt], 0, 0, 0);
                acc[mt][nt] = __builtin_amdgcn_mfma_f32_16x16x32_bf16(al[mt], bh[nt], acc[mt][nt], 0, 0, 0);
            }
    }
}

// ---------------- MLP tail: G -> LDS -> 3 GEMM layers -> out ----------------

__global__ __launch_bounds__(256) void k_mlp3(
    const float* __restrict__ G,
    const unsigned short* __restrict__ Wth3, const unsigned short* __restrict__ Wtl3,
    const float* __restrict__ b3,
    const unsigned short* __restrict__ Wth4, const unsigned short* __restrict__ Wtl4,
    const float* __restrict__ b4,
    const unsigned short* __restrict__ Wth5, const unsigned short* __restrict__ Wtl5,
    const float* __restrict__ b5,
    float* __restrict__ out)
{
    __shared__ float S[MROWS][SROW];
    int tid  = threadIdx.x;
    int lane = tid & 63, wave = tid >> 6;
    int quad = lane >> 4, l16 = lane & 15;
    int nb   = blockIdx.x * MROWS;

    // copy 32 rows of G into S
    for (int u = tid; u < 32 * 64; u += 256) {
        int r = u >> 6, c = u & 63;
        *(float4*)&S[r][c * 4] = *(const float4*)(G + (size_t)(nb + r) * EMB + c * 4);
    }
    __syncthreads();

    f32x4 acc[2][4];

    // mlp1: relu(S @ W3 + b3) -> S
    gemm_layer(S, wave, quad, l16, Wth3, Wtl3, acc);
    __syncthreads();
#pragma unroll
    for (int mt = 0; mt < 2; ++mt)
#pragma unroll
        for (int r = 0; r < 4; ++r) {
            int row = mt * 16 + quad * 4 + r;
#pragma unroll
            for (int nt = 0; nt < 4; ++nt) {
                int col = wave * 64 + nt * 16 + l16;
                S[row][col] = fmaxf(acc[mt][nt][r] + b3[col], 0.f);
            }
        }
    __syncthreads();

    // mlp2: relu(S @ W4 + b4) -> S
    gemm_layer(S, wave, quad, l16, Wth4, Wtl4, acc);
    __syncthreads();
#pragma unroll
    for (int mt = 0; mt < 2; ++mt)
#pragma unroll
        for (int r = 0; r < 4; ++r) {
            int row = mt * 16 + quad * 4 + r;
#pragma unroll
            for (int nt = 0; nt < 4; ++nt) {
                int col = wave * 64 + nt * 16 + l16;
                S[row][col] = fmaxf(acc[mt][nt][r] + b4[col], 0.f);
            }
        }
    __syncthreads();

    // mlp3: S @ W5 + b5 -> global out
    gemm_layer(S, wave, quad, l16, Wth5, Wtl5, acc);
#pragma unroll
    for (int mt = 0; mt < 2; ++mt)
#pragma unroll
        for (int r = 0; r < 4; ++r) {
            int row = nb + mt * 16 + quad * 4 + r;
#pragma unroll
            for (int nt = 0; nt < 4; ++nt) {
                int col = wave * 64 + nt * 16 + l16;
                out[(size_t)row * EMB + col] = acc[mt][nt][r] + b5[col];
            }
        }
}

// ---------------- launch (15 dispatches) ----------------

extern "C" void kernel_launch(void* const* d_in, const int* in_sizes, int n_in,
                              void* d_out, int out_size, void* d_ws, size_t ws_size,
                              hipStream_t stream) {
    const float* x  = (const float*)d_in[0];
    const int*   ei = (const int*)d_in[1];
    const int* src = ei;
    const int* dst = ei + N_EDGES;

    const float* w[6] = {
        (const float*)d_in[2], (const float*)d_in[4], (const float*)d_in[6],
        (const float*)d_in[8], (const float*)d_in[10], (const float*)d_in[12] };
    const float* b[6] = {
        (const float*)d_in[3], (const float*)d_in[5], (const float*)d_in[7],
        (const float*)d_in[9], (const float*)d_in[11], (const float*)d_in[13] };

    char* wsp = (char*)d_ws;
    auto alloc = [&](size_t bytes) {
        char* p = wsp; wsp += (bytes + 255) & ~(size_t)255; return p;
    };
    int*   deg2     = (int*)alloc((size_t)N_NODES * NC * 4);
    int*   cursor2  = (int*)alloc((size_t)N_NODES * NC * 4);
    int*   ro2      = (int*)alloc(((size_t)N_NODES * NC + 1) * 4);
    int*   part     = (int*)alloc(SCAN_NBLK * 4);
    int2*  csr      = (int2*)alloc((size_t)N_EDGES * 8);
    float* dinv     = (float*)alloc(N_NODES * 4);
    unsigned short* wth[6];
    unsigned short* wtl[6];
    wth[0] = (unsigned short*)alloc(EMB * KPAD0 * 2);
    wtl[0] = (unsigned short*)alloc(EMB * KPAD0 * 2);
    for (int i = 1; i < 6; ++i) {
        wth[i] = (unsigned short*)alloc(EMB * EMB * 2);
        wtl[i] = (unsigned short*)alloc(EMB * EMB * 2);
    }
    float* FA = (float*)alloc((size_t)N_NODES * EMB * 4);   // feature buffer
    float* G  = (float*)alloc((size_t)N_NODES * EMB * 4);   // aggregated buffer
    float* FB = (float*)d_out;                               // d_out doubles as scratch

    const int NB_E = (N_EDGES + 255) / 256;               // 1250
    const int NB_N = (N_NODES + 255) / 256;               // 79
    const int NB_I = (N_NODES * NC + 255) / 256;          // 782
    const int MB   = N_NODES / MROWS;                     // 625
    const int AB   = (N_NODES + 3) / 4;                   // 5000 (wave-per-node)

    // chunk-bucketed CSR build (multi-block scan)
    k_init2<<<NB_I, 256, 0, stream>>>(deg2, cursor2, N_NODES * NC);
    k_deg2<<<NB_E, 256, 0, stream>>>(src, dst, deg2, N_EDGES);
    k_scan_part<<<SCAN_NBLK, SCAN_TPB, 0, stream>>>(deg2, part);
    k_scan_root<<<1, SCAN_TPB, 0, stream>>>(part);
    k_scan_write<<<SCAN_NBLK, SCAN_TPB, 0, stream>>>(deg2, part, ro2);
    k_dinv<<<NB_N, 256, 0, stream>>>(ro2, dinv);
    k_scatter2<<<NB_E, 256, 0, stream>>>(src, dst, ro2, cursor2, dinv, csr, N_EDGES);

    // weights: transpose + hi/lo split
    WSplitArgs wa;
    for (int i = 0; i < 6; ++i) { wa.w[i] = w[i]; wa.th[i] = wth[i]; wa.tl[i] = wtl[i]; }
    k_wsplit_all<<<320, 256, 0, stream>>>(wa);

    // conv0 gemm: x @ W0 -> FA
    k_gemm0<<<MB, 256, 0, stream>>>(x, wth[0], wtl[0], FA);

    // conv1: agg(FA)+b0,relu -> G ; G @ W1 -> FB
    k_agg<<<AB, 256, 0, stream>>>(FA, ro2, csr, dinv, b[0], G, 1);
    k_gemm256<<<MB, 256, 0, stream>>>(G, wth[1], wtl[1], FB);

    // conv2: agg(FB)+b1,relu -> G ; G @ W2 -> FA
    k_agg<<<AB, 256, 0, stream>>>(FB, ro2, csr, dinv, b[1], G, 1);
    k_gemm256<<<MB, 256, 0, stream>>>(G, wth[2], wtl[2], FA);

    // tail: agg(FA)+b2 -> G ; G -> mlp1(relu) -> mlp2(relu) -> mlp3 -> out
    k_agg<<<AB, 256, 0, stream>>>(FA, ro2, csr, dinv, b[2], G, 0);
    k_mlp3<<<MB, 256, 0, stream>>>(G,
                                   wth[3], wtl[3], b[3],
                                   wth[4], wtl[4], b[4],
                                   wth[5], wtl[5], b[5],
                                   FB);
}